// Round 9
// baseline (525.937 us; speedup 1.0000x reference)
//
#include <hip/hip_runtime.h>
#include <math.h>

#define NEG_SLOPE 0.2f

typedef _Float16 f16;
typedef _Float16 f16x2 __attribute__((ext_vector_type(2)));
typedef _Float16 f16x4 __attribute__((ext_vector_type(4)));
typedef _Float16 f16x8 __attribute__((ext_vector_type(8)));
typedef float f32x4 __attribute__((ext_vector_type(4)));

static inline int idiv(int a, int b) { return (a + b - 1) / b; }

// Packed activation layout for GEMM-A/B (fragment-major, matches LDS image):
//   elem(row, k) at ((row>>7)*(K>>3) + (k>>3))*128*8 + (row&127)*8 + (k&7)
// Head-major activation layout for edge phase: xl/xr stored [h][N][32] f16,
// so each head's gather region is 3.2MB -> fits one XCD's 4MB L2.

// ---------------- conversions ----------------

__global__ __launch_bounds__(256) void conv_x_packed(const float* __restrict__ x,
                                                     f16* __restrict__ pa, int N) {
    int R = blockIdx.x;
    #pragma unroll
    for (int u = 0; u < 8; ++u) {
        int c = threadIdx.x + u * 256;
        int g = c >> 7, r = c & 127;
        int row = R * 128 + r;
        f16x8 v;
        if (row < N) {
            float4 a = *(const float4*)(x + (size_t)row * 128 + g * 8);
            float4 b = *(const float4*)(x + (size_t)row * 128 + g * 8 + 4);
            v = (f16x8){(f16)a.x, (f16)a.y, (f16)a.z, (f16)a.w,
                        (f16)b.x, (f16)b.y, (f16)b.z, (f16)b.w};
        } else {
            v = (f16x8){0, 0, 0, 0, 0, 0, 0, 0};
        }
        *(f16x8*)(pa + ((size_t)(R * 16 + g) * 128 + r) * 8) = v;
    }
}

__global__ __launch_bounds__(256) void convT_all(
    const float* __restrict__ W1l, const float* __restrict__ W1r,
    const float* __restrict__ W2l, const float* __restrict__ W2r,
    const float* __restrict__ W3l, const float* __restrict__ W3r,
    f16* __restrict__ P1l, f16* __restrict__ P1r,
    f16* __restrict__ P2l, f16* __restrict__ P2r,
    f16* __restrict__ P3l, f16* __restrict__ P3r) {
    __shared__ float tbl[32][33];
    const float* W;
    f16* P;
    int K;
    switch (blockIdx.z) {
        case 0: W = W1l; P = P1l; K = 128; break;
        case 1: W = W1r; P = P1r; K = 128; break;
        case 2: W = W2l; P = P2l; K = 256; break;
        case 3: W = W2r; P = P2r; K = 256; break;
        case 4: W = W3l; P = P3l; K = 256; break;
        default: W = W3r; P = P3r; K = 256; break;
    }
    int bk = blockIdx.x * 32, bc = blockIdx.y * 32;
    if (bk >= K) return;
    int tx = threadIdx.x & 31, ty = threadIdx.x >> 5;
    #pragma unroll
    for (int i = 0; i < 32; i += 8)
        tbl[ty + i][tx] = W[(size_t)(bk + ty + i) * 256 + bc + tx];
    __syncthreads();
    if (threadIdx.x < 128) {
        int cl = threadIdx.x & 31;
        int gl = threadIdx.x >> 5;
        int col = bc + cl;
        int g = (bk >> 3) + gl;
        f16x8 v;
        #pragma unroll
        for (int j = 0; j < 8; ++j) v[j] = (f16)tbl[gl * 8 + j][cl];
        *(f16x8*)(P + ((size_t)((col >> 7) * (K >> 3) + g) * 128 + (col & 127)) * 8) = v;
    }
}

// ---------------- CSR build ----------------

__global__ void hist_kernel(const int* __restrict__ dst, int E, int N, int* __restrict__ cnt) {
    int i = blockIdx.x * blockDim.x + threadIdx.x;
    if (i >= E + N) return;
    int d = (i < E) ? dst[i] : (i - E);
    atomicAdd(&cnt[d], 1);
}

__global__ __launch_bounds__(256) void scanA(const int* __restrict__ cnt,
                                             int* __restrict__ bsum, int N) {
    __shared__ int ws[4];
    int tid = threadIdx.x, lane = tid & 63, wid = tid >> 6;
    int i0 = blockIdx.x * 1024 + tid * 4;
    int s = 0;
    if (i0 + 3 < N) {
        int4 v = *(const int4*)(cnt + i0);
        s = v.x + v.y + v.z + v.w;
    } else {
        for (int j = 0; j < 4; ++j)
            if (i0 + j < N) s += cnt[i0 + j];
    }
    #pragma unroll
    for (int o = 1; o < 64; o <<= 1) s += __shfl_xor(s, o);
    if (lane == 0) ws[wid] = s;
    __syncthreads();
    if (tid == 0) bsum[blockIdx.x] = ws[0] + ws[1] + ws[2] + ws[3];
}

__global__ __launch_bounds__(256) void scanB(int* __restrict__ bsum, int nb) {
    __shared__ int ws[4];
    int tid = threadIdx.x, lane = tid & 63, wid = tid >> 6;
    int v = (tid < nb) ? bsum[tid] : 0;
    int incl = v;
    #pragma unroll
    for (int o = 1; o < 64; o <<= 1) {
        int t = __shfl_up(incl, o);
        if (lane >= o) incl += t;
    }
    if (lane == 63) ws[wid] = incl;
    __syncthreads();
    int add = 0;
    for (int w = 0; w < wid; ++w) add += ws[w];
    if (tid < nb) bsum[tid] = add + incl - v;
}

__global__ __launch_bounds__(256) void scanC(const int* __restrict__ cnt,
                                             const int* __restrict__ bsum,
                                             int* __restrict__ rp, int* __restrict__ wofs, int N) {
    __shared__ int ws[4];
    __shared__ int base_s;
    int tid = threadIdx.x, lane = tid & 63, wid = tid >> 6;
    int i0 = blockIdx.x * 1024 + tid * 4;
    int v0 = (i0 + 0 < N) ? cnt[i0 + 0] : 0;
    int v1 = (i0 + 1 < N) ? cnt[i0 + 1] : 0;
    int v2 = (i0 + 2 < N) ? cnt[i0 + 2] : 0;
    int v3 = (i0 + 3 < N) ? cnt[i0 + 3] : 0;
    int t4 = v0 + v1 + v2 + v3;
    int incl = t4;
    #pragma unroll
    for (int o = 1; o < 64; o <<= 1) {
        int t = __shfl_up(incl, o);
        if (lane >= o) incl += t;
    }
    if (lane == 63) ws[wid] = incl;
    if (tid == 0) base_s = bsum[blockIdx.x];
    __syncthreads();
    int wadd = 0;
    for (int w = 0; w < wid; ++w) wadd += ws[w];
    int pre = base_s + wadd + incl - t4;
    int p1 = pre + v0, p2 = p1 + v1, p3 = p2 + v2, p4 = p3 + v3;
    if (i0 + 0 < N) { wofs[i0 + 0] = pre; rp[i0 + 1] = p1; }
    if (i0 + 1 < N) { wofs[i0 + 1] = p1;  rp[i0 + 2] = p2; }
    if (i0 + 2 < N) { wofs[i0 + 2] = p2;  rp[i0 + 3] = p3; }
    if (i0 + 3 < N) { wofs[i0 + 3] = p3;  rp[i0 + 4] = p4; }
    if (blockIdx.x == 0 && tid == 0) rp[0] = 0;
}

__global__ void scatter_kernel(const int* __restrict__ src, const int* __restrict__ dst,
                               int E, int N, int* __restrict__ wofs, int* __restrict__ sorted_src) {
    int i = blockIdx.x * blockDim.x + threadIdx.x;
    if (i >= E + N) return;
    int d, s;
    if (i < E) { d = dst[i]; s = src[i]; } else { d = i - E; s = d; }
    int pos = atomicAdd(&wofs[d], 1);
    sorted_src[pos] = s;
}

// ------------- degree-bucketed perm, LDS-privatized (cheap, low contention) -------------

__global__ __launch_bounds__(256) void deg_hist(const int* __restrict__ rp, int N,
                                                int* __restrict__ dcnt) {
    __shared__ int l[64];
    if (threadIdx.x < 64) l[threadIdx.x] = 0;
    __syncthreads();
    int i = blockIdx.x * 256 + threadIdx.x;
    if (i < N) atomicAdd(&l[min(rp[i + 1] - rp[i], 63)], 1);
    __syncthreads();
    if (threadIdx.x < 64 && l[threadIdx.x]) atomicAdd(&dcnt[threadIdx.x], l[threadIdx.x]);
}

__global__ void deg_scan(int* __restrict__ dcnt) {  // 1 block, 64 threads -> exclusive
    int tid = threadIdx.x;
    int v = dcnt[tid];
    int incl = v;
    #pragma unroll
    for (int o = 1; o < 64; o <<= 1) {
        int t = __shfl_up(incl, o);
        if (tid >= o) incl += t;
    }
    dcnt[tid] = incl - v;
}

__global__ __launch_bounds__(256) void deg_scatter(const int* __restrict__ rp, int N,
                                                   int* __restrict__ gofs,
                                                   int* __restrict__ perm) {
    __shared__ int lcnt[64];
    __shared__ int lbase[64];
    int tid = threadIdx.x;
    if (tid < 64) lcnt[tid] = 0;
    __syncthreads();
    int i = blockIdx.x * 256 + tid;
    int deg = 0, lrank = 0;
    if (i < N) {
        deg = min(rp[i + 1] - rp[i], 63);
        lrank = atomicAdd(&lcnt[deg], 1);  // LDS atomic: local rank
    }
    __syncthreads();
    if (tid < 64 && lcnt[tid] > 0) lbase[tid] = atomicAdd(&gofs[tid], lcnt[tid]);
    __syncthreads();
    if (i < N) perm[lbase[deg] + lrank] = i;
}

// ---------------- MFMA GEMM on packed inputs, head-major C writes ----------------

__device__ __forceinline__ void gll16(const f16* g, f16* l) {
#if __has_builtin(__builtin_amdgcn_global_load_lds)
    __builtin_amdgcn_global_load_lds((const __attribute__((address_space(1))) void*)g,
                                     (__attribute__((address_space(3))) void*)l, 16, 0, 0);
#else
    *(f16x8*)l = *(const f16x8*)g;
#endif
}

__global__ __launch_bounds__(256) void gemm16_packed(
    const f16* __restrict__ PA, int N, int K,
    const f16* __restrict__ PBl, const f16* __restrict__ PBr,
    f16* __restrict__ Cl, f16* __restrict__ Cr) {
    __shared__ f16 lds[2][2][8192];  // 64KB
    const int nblk = gridDim.x;
    int bid = blockIdx.x;
    int xcd = bid & 7, jj = bid >> 3;
    int nper = nblk >> 3, rem = nblk & 7;
    int slot = (xcd < rem) ? xcd * (nper + 1) + jj
                           : rem * (nper + 1) + (xcd - rem) * nper + jj;
    int R = slot >> 2, by = slot & 3;
    const f16* __restrict__ PB = (by >> 1) ? PBr : PBl;
    f16* __restrict__ C = (by >> 1) ? Cr : Cl;
    const int cb = by & 1;
    const int row0 = R * 128;
    const int col0 = cb * 128;
    const f16* Abase = PA + (size_t)R * 128 * K;
    const f16* Bbase = PB + (size_t)cb * 128 * K;
    const int t = threadIdx.x;
    const int lane = t & 63, wid = t >> 6;
    const int wr = (wid >> 1) * 64, wc = (wid & 1) * 64;
    const int lg = lane >> 4, lr = lane & 15;

    f32x4 acc[4][4];
    #pragma unroll
    for (int m = 0; m < 4; ++m)
        #pragma unroll
        for (int n = 0; n < 4; ++n) acc[m][n] = (f32x4){0.f, 0.f, 0.f, 0.f};

    auto stage = [&](int buf, int k0) {
        const f16* As = Abase + (size_t)k0 * 128 + t * 8;
        const f16* Bs = Bbase + (size_t)k0 * 128 + t * 8;
        f16* Al = &lds[buf][0][t * 8];
        f16* Bl = &lds[buf][1][t * 8];
        #pragma unroll
        for (int u = 0; u < 4; ++u) gll16(As + u * 2048, Al + u * 2048);
        #pragma unroll
        for (int u = 0; u < 4; ++u) gll16(Bs + u * 2048, Bl + u * 2048);
    };

    const int nk = K >> 6;
    stage(0, 0);
    asm volatile("s_waitcnt vmcnt(0)" ::: "memory");
    __syncthreads();
    for (int c = 0; c < nk; ++c) {
        if (c + 1 < nk) stage((c + 1) & 1, (c + 1) * 64);
        f16x8* Asp = (f16x8*)lds[c & 1][0];
        f16x8* Bsp = (f16x8*)lds[c & 1][1];
        #pragma unroll
        for (int s = 0; s < 2; ++s) {
            f16x8 af[4], bf[4];
            #pragma unroll
            for (int m = 0; m < 4; ++m) af[m] = Asp[(s * 4 + lg) * 128 + wr + m * 16 + lr];
            #pragma unroll
            for (int n = 0; n < 4; ++n) bf[n] = Bsp[(s * 4 + lg) * 128 + wc + n * 16 + lr];
            #pragma unroll
            for (int m = 0; m < 4; ++m)
                #pragma unroll
                for (int n = 0; n < 4; ++n)
                    acc[m][n] = __builtin_amdgcn_mfma_f32_16x16x32_f16(af[m], bf[n], acc[m][n], 0, 0, 0);
        }
        asm volatile("s_waitcnt vmcnt(0)" ::: "memory");
        __syncthreads();
    }
    // epilogue: head-major C [h][N][32]; col groups of 16 never cross a head boundary
    const size_t hs = (size_t)N * 32;
    #pragma unroll
    for (int m = 0; m < 4; ++m) {
        int row_b = row0 + wr + m * 16 + lg * 4;
        #pragma unroll
        for (int reg = 0; reg < 4; ++reg) {
            int row = row_b + reg;
            if (row < N) {
                #pragma unroll
                for (int n = 0; n < 4; ++n) {
                    int col = col0 + wc + n * 16 + lr;
                    C[hs * (col >> 5) + (size_t)row * 32 + (col & 31)] = (f16)acc[m][n][reg];
                }
            }
        }
    }
}

// ---------------- small GEMM layer 4 ----------------

__global__ __launch_bounds__(256) void gemm_small16(
    const f16* __restrict__ A, int N,
    const float* __restrict__ Wl, const float* __restrict__ Wr,
    float* __restrict__ Cl, float* __restrict__ Cr) {
    const int K = 256, M = 16;
    __shared__ float As[16][260];
    __shared__ float Ws[256 * 16];
    const float* __restrict__ W = (blockIdx.y == 0) ? Wl : Wr;
    float* __restrict__ C = (blockIdx.y == 0) ? Cl : Cr;
    int row0 = blockIdx.x * 16;
    int tid = threadIdx.x;
    {
        #pragma unroll
        for (int u = 0; u < 4; ++u)
            *(float4*)&Ws[tid * 16 + u * 4] = *(const float4*)(W + tid * 16 + u * 4);
        int r = tid >> 4;
        int c = (tid & 15) * 16;
        int row = row0 + r;
        if (row < N) {
            int R = row >> 7, rr = row & 127;
            const f16* base = A + ((size_t)(R * 32 + (c >> 3)) * 128 + rr) * 8;
            f16x8 v0 = *(const f16x8*)base;
            f16x8 v1 = *(const f16x8*)(base + 1024);
            #pragma unroll
            for (int j = 0; j < 8; ++j) {
                As[r][c + j] = (float)v0[j];
                As[r][c + 8 + j] = (float)v1[j];
            }
        } else {
            #pragma unroll
            for (int j = 0; j < 16; ++j) As[r][c + j] = 0.f;
        }
    }
    __syncthreads();
    int r = tid >> 4;
    int col = tid & 15;
    float acc = 0.f;
    #pragma unroll 8
    for (int k = 0; k < K; ++k) acc = fmaf(As[r][k], Ws[k * M + col], acc);
    int row = row0 + r;
    if (row < N) C[(size_t)row * M + col] = acc;
}

// ------- edge kernel: head-split (h=bid&7 -> XCD-local 3.2MB region) + degree-sorted ----
// 4 lanes x f16x8 per (node,head) task: 8 dims/lane like the efficient round-6 body,
// 64 tasks/block, wave-mates have near-equal degree via perm -> minimal tail waste.

__global__ __launch_bounds__(256) void edge_h8_sorted(
    const f16* __restrict__ xl, const f16* __restrict__ xr,
    const int* __restrict__ rp, const int* __restrict__ ss,
    const int* __restrict__ perm,
    const float* __restrict__ att, const float* __restrict__ bias,
    f16* __restrict__ hout, int N) {
    int bid = blockIdx.x;
    int h = bid & 7;
    int tile = bid >> 3;
    int tid = threadIdx.x;
    int task = tile * 64 + (tid >> 2);
    if (task >= N) return;
    int n = perm[task];
    int ll = tid & 3;  // dims h*32 + ll*8 .. +8
    const size_t hs = (size_t)N * 32;
    const f16* xlh = xl + hs * h;
    const int doff = h * 32 + ll * 8;
    f16x8 xrr = *(const f16x8*)(xr + hs * h + (size_t)n * 32 + ll * 8);
    float4 atlo = *(const float4*)(att + doff);
    float4 athi = *(const float4*)(att + doff + 4);
    f16x2 at01 = {(f16)atlo.x, (f16)atlo.y};
    f16x2 at23 = {(f16)atlo.z, (f16)atlo.w};
    f16x2 at45 = {(f16)athi.x, (f16)athi.y};
    f16x2 at67 = {(f16)athi.z, (f16)athi.w};
    const f16 ns = (f16)NEG_SLOPE;
    float m = -INFINITY, s = 0.f;
    f16x8 a = {0, 0, 0, 0, 0, 0, 0, 0};
    int beg = rp[n], end = rp[n + 1];
    int last = end - 1;
    const f16* xb = xlh + ll * 8;
    f16x8 r0 = *(const f16x8*)(xb + (size_t)ss[beg] * 32);
    f16x8 r1 = *(const f16x8*)(xb + (size_t)ss[min(beg + 1, last)] * 32);
    f16x8 r2 = *(const f16x8*)(xb + (size_t)ss[min(beg + 2, last)] * 32);
    f16x8 r3 = *(const f16x8*)(xb + (size_t)ss[min(beg + 3, last)] * 32);
    int j4 = ss[min(beg + 4, last)];
    int j5 = ss[min(beg + 5, last)];

    auto score = [&](const f16x8& cur) -> float {
        f16x8 g = cur + xrr;
        f16x8 gs = g * ns;
        f16x8 lk = __builtin_elementwise_max(g, gs);
#if __has_builtin(__builtin_amdgcn_fdot2)
        f16x2 l01 = __builtin_shufflevector(lk, lk, 0, 1);
        f16x2 l23 = __builtin_shufflevector(lk, lk, 2, 3);
        f16x2 l45 = __builtin_shufflevector(lk, lk, 4, 5);
        f16x2 l67 = __builtin_shufflevector(lk, lk, 6, 7);
        float p = __builtin_amdgcn_fdot2(l01, at01, 0.f, false);
        p = __builtin_amdgcn_fdot2(l23, at23, p, false);
        p = __builtin_amdgcn_fdot2(l45, at45, p, false);
        p = __builtin_amdgcn_fdot2(l67, at67, p, false);
#else
        float p = (float)lk[0] * atlo.x + (float)lk[1] * atlo.y +
                  (float)lk[2] * atlo.z + (float)lk[3] * atlo.w +
                  (float)lk[4] * athi.x + (float)lk[5] * athi.y +
                  (float)lk[6] * athi.z + (float)lk[7] * athi.w;
#endif
        return p;
    };

    int i = beg;
    for (; i + 1 < end; i += 2) {
        f16x8 c0 = r0, c1 = r1;
        r0 = r2; r1 = r3;
        r2 = *(const f16x8*)(xb + (size_t)j4 * 32);
        r3 = *(const f16x8*)(xb + (size_t)j5 * 32);
        j4 = ss[min(i + 6, last)];
        j5 = ss[min(i + 7, last)];
        float p0 = score(c0);
        float p1 = score(c1);
        p0 += __shfl_xor(p0, 1);
        p1 += __shfl_xor(p1, 1);
        p0 += __shfl_xor(p0, 2);
        p1 += __shfl_xor(p1, 2);  // 4-lane task reduce
        float d0 = p0 - m, d1 = p1 - m;
        if (__any(fmaxf(d0, d1) > 4.f)) {
            float mn = fmaxf(m, fmaxf(p0, p1));
            float cf = __expf(m - mn);  // exp(-inf)=0 handles init
            s *= cf;
            f16 cfh = (f16)cf;
            a = a * (f16x8){cfh, cfh, cfh, cfh, cfh, cfh, cfh, cfh};
            m = mn;
            d0 = p0 - m; d1 = p1 - m;
        }
        float e0 = __expf(d0);
        float e1 = __expf(d1);
        s += e0 + e1;
        f16 e0h = (f16)e0, e1h = (f16)e1;
        f16x8 e0v = {e0h, e0h, e0h, e0h, e0h, e0h, e0h, e0h};
        f16x8 e1v = {e1h, e1h, e1h, e1h, e1h, e1h, e1h, e1h};
#if __has_builtin(__builtin_elementwise_fma)
        a = __builtin_elementwise_fma(c0, e0v, a);
        a = __builtin_elementwise_fma(c1, e1v, a);
#else
        a = a + c0 * e0v + c1 * e1v;
#endif
    }
    if (i < end) {  // odd tail
        f16x8 c0 = r0;
        float p0 = score(c0);
        p0 += __shfl_xor(p0, 1);
        p0 += __shfl_xor(p0, 2);
        float d0 = p0 - m;
        if (__any(d0 > 4.f)) {
            float mn = fmaxf(m, p0);
            float cf = __expf(m - mn);
            s *= cf;
            f16 cfh = (f16)cf;
            a = a * (f16x8){cfh, cfh, cfh, cfh, cfh, cfh, cfh, cfh};
            m = mn;
            d0 = p0 - m;
        }
        float e0 = __expf(d0);
        s += e0;
        f16 e0h = (f16)e0;
        f16x8 e0v = {e0h, e0h, e0h, e0h, e0h, e0h, e0h, e0h};
#if __has_builtin(__builtin_elementwise_fma)
        a = __builtin_elementwise_fma(c0, e0v, a);
#else
        a = a + c0 * e0v;
#endif
    }
    float inv = 1.f / (s + 1e-16f);
    float4 blo = *(const float4*)(bias + doff);
    float4 bhi = *(const float4*)(bias + doff + 4);
    float o[8];
    o[0] = (float)a[0] * inv + blo.x; o[1] = (float)a[1] * inv + blo.y;
    o[2] = (float)a[2] * inv + blo.z; o[3] = (float)a[3] * inv + blo.w;
    o[4] = (float)a[4] * inv + bhi.x; o[5] = (float)a[5] * inv + bhi.y;
    o[6] = (float)a[6] * inv + bhi.z; o[7] = (float)a[7] * inv + bhi.w;
    f16x8 ov;
    #pragma unroll
    for (int j = 0; j < 8; ++j) {
        float e = o[j] > 0.f ? o[j] : __expf(o[j]) - 1.f;  // elu
        ov[j] = (f16)e;
    }
    // packed PH write: k-range h*32+ll*8 -> chunk 4h+ll, contiguous f16x8
    *(f16x8*)(hout + ((size_t)((n >> 7) * 32 + 4 * h + ll) * 128 + (n & 127)) * 8) = ov;
}

// ---------------- edge kernel layer 4: degree-sorted, four nodes/wave ----------------

__global__ __launch_bounds__(256) void edge_h1_kernel(
    const float* __restrict__ xl, const float* __restrict__ xr,
    const int* __restrict__ rp, const int* __restrict__ ss,
    const int* __restrict__ perm,
    const float* __restrict__ att, const float* __restrict__ bias,
    float* __restrict__ out, int N) {
    int tid = threadIdx.x;
    int grp = tid >> 4;
    int gl = tid & 15;
    int task = blockIdx.x * 16 + grp;
    if (task >= N) return;
    int n = perm[task];
    float xrv = xr[(size_t)n * 16 + gl];
    float attv = att[gl];
    float bv = bias[gl];
    float m = -INFINITY, s = 0.f, acc = 0.f;
    int beg = rp[n], end = rp[n + 1], last = end - 1;
    const float* xb = xl + gl;
    float x0 = xb[(size_t)ss[beg] * 16];
    float x1 = xb[(size_t)ss[min(beg + 1, last)] * 16];
    float x2 = xb[(size_t)ss[min(beg + 2, last)] * 16];
    float x3 = xb[(size_t)ss[min(beg + 3, last)] * 16];
    int j4 = ss[min(beg + 4, last)];
    int j5 = ss[min(beg + 5, last)];
    int i = beg;
    for (; i + 1 < end; i += 2) {
        float c0 = x0, c1 = x1;
        x0 = x2; x1 = x3;
        x2 = xb[(size_t)j4 * 16];
        x3 = xb[(size_t)j5 * 16];
        j4 = ss[min(i + 6, last)];
        j5 = ss[min(i + 7, last)];
        float g0 = c0 + xrv, g1 = c1 + xrv;
        float p0 = attv * fmaxf(g0, NEG_SLOPE * g0);
        float p1 = attv * fmaxf(g1, NEG_SLOPE * g1);
        p0 += __shfl_xor(p0, 1); p1 += __shfl_xor(p1, 1);
        p0 += __shfl_xor(p0, 2); p1 += __shfl_xor(p1, 2);
        p0 += __shfl_xor(p0, 4); p1 += __shfl_xor(p1, 4);
        p0 += __shfl_xor(p0, 8); p1 += __shfl_xor(p1, 8);
        float d0 = p0 - m, d1 = p1 - m;
        if (__any(fmaxf(d0, d1) > 8.f)) {
            float mn = fmaxf(m, fmaxf(p0, p1));
            float cf = __expf(m - mn);
            s *= cf; acc *= cf;
            m = mn;
            d0 = p0 - m; d1 = p1 - m;
        }
        float e0 = __expf(d0), e1 = __expf(d1);
        s += e0 + e1;
        acc = fmaf(e1, c1, fmaf(e0, c0, acc));
    }
    if (i < end) {
        float c0 = x0;
        float g0 = c0 + xrv;
        float p0 = attv * fmaxf(g0, NEG_SLOPE * g0);
        p0 += __shfl_xor(p0, 1);
        p0 += __shfl_xor(p0, 2);
        p0 += __shfl_xor(p0, 4);
        p0 += __shfl_xor(p0, 8);
        float d0 = p0 - m;
        if (__any(d0 > 8.f)) {
            float mn = fmaxf(m, p0);
            float cf = __expf(m - mn);
            s *= cf; acc *= cf;
            m = mn;
            d0 = p0 - m;
        }
        float e0 = __expf(d0);
        s += e0;
        acc = fmaf(e0, c0, acc);
    }
    float v = acc / (s + 1e-16f) + bv;
    float mx = v;
    mx = fmaxf(mx, __shfl_xor(mx, 1));
    mx = fmaxf(mx, __shfl_xor(mx, 2));
    mx = fmaxf(mx, __shfl_xor(mx, 4));
    mx = fmaxf(mx, __shfl_xor(mx, 8));
    float ex = __expf(v - mx);
    float se = ex;
    se += __shfl_xor(se, 1);
    se += __shfl_xor(se, 2);
    se += __shfl_xor(se, 4);
    se += __shfl_xor(se, 8);
    out[(size_t)n * 16 + gl] = v - mx - __logf(se);
}

// ---------------- launch ----------------

extern "C" void kernel_launch(void* const* d_in, const int* in_sizes, int n_in,
                              void* d_out, int out_size, void* d_ws, size_t ws_size,
                              hipStream_t stream) {
    const float* x    = (const float*)d_in[0];
    const int*   ei   = (const int*)d_in[1];
    const float* Wl1  = (const float*)d_in[2];
    const float* Wr1  = (const float*)d_in[3];
    const float* att1 = (const float*)d_in[4];
    const float* b1   = (const float*)d_in[5];
    const float* Wl2  = (const float*)d_in[6];
    const float* Wr2  = (const float*)d_in[7];
    const float* att2 = (const float*)d_in[8];
    const float* b2   = (const float*)d_in[9];
    const float* Wl3  = (const float*)d_in[10];
    const float* Wr3  = (const float*)d_in[11];
    const float* att3 = (const float*)d_in[12];
    const float* b3   = (const float*)d_in[13];
    const float* Wl4  = (const float*)d_in[14];
    const float* Wr4  = (const float*)d_in[15];
    const float* att4 = (const float*)d_in[16];
    const float* b4   = (const float*)d_in[17];

    const int N = in_sizes[0] / 128;
    const int E = in_sizes[1] / 2;
    const int* src = ei;
    const int* dst = ei + E;
    const int Etot = E + N;
    const int ntile = idiv(N, 128);

    char* wsb = (char*)d_ws;
    size_t off = 0;
    auto alloc = [&](size_t bytes) -> void* {
        void* p = wsb + off;
        off += (bytes + 255) & ~(size_t)255;
        return p;
    };
    f16*   PX   = (f16*)alloc((size_t)ntile * 128 * 128 * 2);
    f16*   PH   = (f16*)alloc((size_t)ntile * 128 * 256 * 2);
    f16*   xl16 = (f16*)alloc((size_t)N * 256 * 2);   // head-major [8][N][32]
    f16*   xr16 = (f16*)alloc((size_t)N * 256 * 2);   // head-major [8][N][32]
    float* xl4  = (float*)alloc((size_t)N * 16 * 4);
    float* xr4  = (float*)alloc((size_t)N * 16 * 4);
    f16*   PB1l = (f16*)alloc((size_t)256 * 128 * 2);
    f16*   PB1r = (f16*)alloc((size_t)256 * 128 * 2);
    f16*   PB2l = (f16*)alloc((size_t)256 * 256 * 2);
    f16*   PB2r = (f16*)alloc((size_t)256 * 256 * 2);
    f16*   PB3l = (f16*)alloc((size_t)256 * 256 * 2);
    f16*   PB3r = (f16*)alloc((size_t)256 * 256 * 2);
    int*   cnt  = (int*)alloc((size_t)N * 4);
    int*   wof  = (int*)alloc((size_t)N * 4);
    int*   rp   = (int*)alloc((size_t)(N + 1) * 4);
    int*   ss   = (int*)alloc((size_t)Etot * 4);
    int*   bsum = (int*)alloc((size_t)idiv(N, 1024) * 4);
    int*   dcnt = (int*)alloc(64 * 4);
    int*   perm = (int*)alloc((size_t)N * 4);

    // conversions
    conv_x_packed<<<ntile, 256, 0, stream>>>(x, PX, N);
    convT_all<<<dim3(8, 8, 6), 256, 0, stream>>>(Wl1, Wr1, Wl2, Wr2, Wl3, Wr3,
                                                 PB1l, PB1r, PB2l, PB2r, PB3l, PB3r);

    // CSR build
    hipMemsetAsync(cnt, 0, (size_t)N * 4, stream);
    hipMemsetAsync(dcnt, 0, 64 * 4, stream);
    hist_kernel<<<idiv(Etot, 256), 256, 0, stream>>>(dst, E, N, cnt);
    const int nb = idiv(N, 1024);
    scanA<<<nb, 256, 0, stream>>>(cnt, bsum, N);
    scanB<<<1, 256, 0, stream>>>(bsum, nb);
    scanC<<<nb, 256, 0, stream>>>(cnt, bsum, rp, wof, N);
    scatter_kernel<<<idiv(Etot, 256), 256, 0, stream>>>(src, dst, E, N, wof, ss);
    // degree-bucketed perm (LDS-privatized, cheap)
    deg_hist<<<idiv(N, 256), 256, 0, stream>>>(rp, N, dcnt);
    deg_scan<<<1, 64, 0, stream>>>(dcnt);
    deg_scatter<<<idiv(N, 256), 256, 0, stream>>>(rp, N, dcnt, perm);

    const int nblk = ntile * 4;
    const int egrid = idiv(N, 64) * 8;
    // layer 1 (K=128)
    gemm16_packed<<<nblk, 256, 0, stream>>>(PX, N, 128, PB1l, PB1r, xl16, xr16);
    edge_h8_sorted<<<egrid, 256, 0, stream>>>(xl16, xr16, rp, ss, perm, att1, b1, PH, N);
    // layer 2
    gemm16_packed<<<nblk, 256, 0, stream>>>(PH, N, 256, PB2l, PB2r, xl16, xr16);
    edge_h8_sorted<<<egrid, 256, 0, stream>>>(xl16, xr16, rp, ss, perm, att2, b2, PH, N);
    // layer 3
    gemm16_packed<<<nblk, 256, 0, stream>>>(PH, N, 256, PB3l, PB3r, xl16, xr16);
    edge_h8_sorted<<<egrid, 256, 0, stream>>>(xl16, xr16, rp, ss, perm, att3, b3, PH, N);
    // layer 4 (M=16) + fused log_softmax
    gemm_small16<<<dim3(idiv(N, 16), 2), 256, 0, stream>>>(PH, N, Wl4, Wr4, xl4, xr4);
    edge_h1_kernel<<<idiv(N, 16), 256, 0, stream>>>(xl4, xr4, rp, ss, perm, att4, b4,
                                                    (float*)d_out, N);
}

// Round 10
// 497.189 us; speedup vs baseline: 1.0578x; 1.0578x over previous
//
#include <hip/hip_runtime.h>
#include <math.h>

#define NEG_SLOPE 0.2f

typedef _Float16 f16;
typedef _Float16 f16x2 __attribute__((ext_vector_type(2)));
typedef _Float16 f16x4 __attribute__((ext_vector_type(4)));
typedef _Float16 f16x8 __attribute__((ext_vector_type(8)));
typedef float f32x4 __attribute__((ext_vector_type(4)));

static inline int idiv(int a, int b) { return (a + b - 1) / b; }

// Packed activation layout for GEMM-A/B (fragment-major, matches LDS image):
//   elem(row, k) at ((row>>7)*(K>>3) + (k>>3))*128*8 + (row&127)*8 + (k&7)
// Head-major activation layout for edge phase: xl/xr stored [h][N][32] f16,
// so each head's gather region is 3.2MB -> fits one XCD's 4MB L2.

// ---------------- conversions ----------------

__global__ __launch_bounds__(256) void conv_x_packed(const float* __restrict__ x,
                                                     f16* __restrict__ pa, int N) {
    int R = blockIdx.x;
    #pragma unroll
    for (int u = 0; u < 8; ++u) {
        int c = threadIdx.x + u * 256;
        int g = c >> 7, r = c & 127;
        int row = R * 128 + r;
        f16x8 v;
        if (row < N) {
            float4 a = *(const float4*)(x + (size_t)row * 128 + g * 8);
            float4 b = *(const float4*)(x + (size_t)row * 128 + g * 8 + 4);
            v = (f16x8){(f16)a.x, (f16)a.y, (f16)a.z, (f16)a.w,
                        (f16)b.x, (f16)b.y, (f16)b.z, (f16)b.w};
        } else {
            v = (f16x8){0, 0, 0, 0, 0, 0, 0, 0};
        }
        *(f16x8*)(pa + ((size_t)(R * 16 + g) * 128 + r) * 8) = v;
    }
}

__global__ __launch_bounds__(256) void convT_all(
    const float* __restrict__ W1l, const float* __restrict__ W1r,
    const float* __restrict__ W2l, const float* __restrict__ W2r,
    const float* __restrict__ W3l, const float* __restrict__ W3r,
    f16* __restrict__ P1l, f16* __restrict__ P1r,
    f16* __restrict__ P2l, f16* __restrict__ P2r,
    f16* __restrict__ P3l, f16* __restrict__ P3r) {
    __shared__ float tbl[32][33];
    const float* W;
    f16* P;
    int K;
    switch (blockIdx.z) {
        case 0: W = W1l; P = P1l; K = 128; break;
        case 1: W = W1r; P = P1r; K = 128; break;
        case 2: W = W2l; P = P2l; K = 256; break;
        case 3: W = W2r; P = P2r; K = 256; break;
        case 4: W = W3l; P = P3l; K = 256; break;
        default: W = W3r; P = P3r; K = 256; break;
    }
    int bk = blockIdx.x * 32, bc = blockIdx.y * 32;
    if (bk >= K) return;
    int tx = threadIdx.x & 31, ty = threadIdx.x >> 5;
    #pragma unroll
    for (int i = 0; i < 32; i += 8)
        tbl[ty + i][tx] = W[(size_t)(bk + ty + i) * 256 + bc + tx];
    __syncthreads();
    if (threadIdx.x < 128) {
        int cl = threadIdx.x & 31;
        int gl = threadIdx.x >> 5;
        int col = bc + cl;
        int g = (bk >> 3) + gl;
        f16x8 v;
        #pragma unroll
        for (int j = 0; j < 8; ++j) v[j] = (f16)tbl[gl * 8 + j][cl];
        *(f16x8*)(P + ((size_t)((col >> 7) * (K >> 3) + g) * 128 + (col & 127)) * 8) = v;
    }
}

// ---------------- CSR build ----------------

__global__ void hist_kernel(const int* __restrict__ dst, int E, int N, int* __restrict__ cnt) {
    int i = blockIdx.x * blockDim.x + threadIdx.x;
    if (i >= E + N) return;
    int d = (i < E) ? dst[i] : (i - E);
    atomicAdd(&cnt[d], 1);
}

__global__ __launch_bounds__(256) void scanA(const int* __restrict__ cnt,
                                             int* __restrict__ bsum, int N) {
    __shared__ int ws[4];
    int tid = threadIdx.x, lane = tid & 63, wid = tid >> 6;
    int i0 = blockIdx.x * 1024 + tid * 4;
    int s = 0;
    if (i0 + 3 < N) {
        int4 v = *(const int4*)(cnt + i0);
        s = v.x + v.y + v.z + v.w;
    } else {
        for (int j = 0; j < 4; ++j)
            if (i0 + j < N) s += cnt[i0 + j];
    }
    #pragma unroll
    for (int o = 1; o < 64; o <<= 1) s += __shfl_xor(s, o);
    if (lane == 0) ws[wid] = s;
    __syncthreads();
    if (tid == 0) bsum[blockIdx.x] = ws[0] + ws[1] + ws[2] + ws[3];
}

__global__ __launch_bounds__(256) void scanB(int* __restrict__ bsum, int nb) {
    __shared__ int ws[4];
    int tid = threadIdx.x, lane = tid & 63, wid = tid >> 6;
    int v = (tid < nb) ? bsum[tid] : 0;
    int incl = v;
    #pragma unroll
    for (int o = 1; o < 64; o <<= 1) {
        int t = __shfl_up(incl, o);
        if (lane >= o) incl += t;
    }
    if (lane == 63) ws[wid] = incl;
    __syncthreads();
    int add = 0;
    for (int w = 0; w < wid; ++w) add += ws[w];
    if (tid < nb) bsum[tid] = add + incl - v;
}

__global__ __launch_bounds__(256) void scanC(const int* __restrict__ cnt,
                                             const int* __restrict__ bsum,
                                             int* __restrict__ rp, int* __restrict__ wofs, int N) {
    __shared__ int ws[4];
    __shared__ int base_s;
    int tid = threadIdx.x, lane = tid & 63, wid = tid >> 6;
    int i0 = blockIdx.x * 1024 + tid * 4;
    int v0 = (i0 + 0 < N) ? cnt[i0 + 0] : 0;
    int v1 = (i0 + 1 < N) ? cnt[i0 + 1] : 0;
    int v2 = (i0 + 2 < N) ? cnt[i0 + 2] : 0;
    int v3 = (i0 + 3 < N) ? cnt[i0 + 3] : 0;
    int t4 = v0 + v1 + v2 + v3;
    int incl = t4;
    #pragma unroll
    for (int o = 1; o < 64; o <<= 1) {
        int t = __shfl_up(incl, o);
        if (lane >= o) incl += t;
    }
    if (lane == 63) ws[wid] = incl;
    if (tid == 0) base_s = bsum[blockIdx.x];
    __syncthreads();
    int wadd = 0;
    for (int w = 0; w < wid; ++w) wadd += ws[w];
    int pre = base_s + wadd + incl - t4;
    int p1 = pre + v0, p2 = p1 + v1, p3 = p2 + v2, p4 = p3 + v3;
    if (i0 + 0 < N) { wofs[i0 + 0] = pre; rp[i0 + 1] = p1; }
    if (i0 + 1 < N) { wofs[i0 + 1] = p1;  rp[i0 + 2] = p2; }
    if (i0 + 2 < N) { wofs[i0 + 2] = p2;  rp[i0 + 3] = p3; }
    if (i0 + 3 < N) { wofs[i0 + 3] = p3;  rp[i0 + 4] = p4; }
    if (blockIdx.x == 0 && tid == 0) rp[0] = 0;
}

__global__ void scatter_kernel(const int* __restrict__ src, const int* __restrict__ dst,
                               int E, int N, int* __restrict__ wofs, int* __restrict__ sorted_src) {
    int i = blockIdx.x * blockDim.x + threadIdx.x;
    if (i >= E + N) return;
    int d, s;
    if (i < E) { d = dst[i]; s = src[i]; } else { d = i - E; s = d; }
    int pos = atomicAdd(&wofs[d], 1);
    sorted_src[pos] = s;
}

// ------- tile-local degree sort: 1024-node tiles, LDS-only, preserves locality -------
// perm only reorders scheduling; per-node numerics are unchanged (each task consumes
// its own node's full edge list in CSR order).

__global__ __launch_bounds__(256) void tile_sort(const int* __restrict__ rp, int N,
                                                 int* __restrict__ perm) {
    __shared__ int hist[64];
    __shared__ int base[64];
    int tile0 = blockIdx.x * 1024;
    int tid = threadIdx.x;
    if (tid < 64) hist[tid] = 0;
    __syncthreads();
    int deg[4], lrank[4];
    #pragma unroll
    for (int u = 0; u < 4; ++u) {
        int i = tile0 + tid + u * 256;
        if (i < N) {
            deg[u] = min(rp[i + 1] - rp[i], 63);
            lrank[u] = atomicAdd(&hist[deg[u]], 1);
        }
    }
    __syncthreads();
    if (tid < 64) {  // one wave: exclusive scan of 64 buckets
        int v = hist[tid];
        int incl = v;
        #pragma unroll
        for (int o = 1; o < 64; o <<= 1) {
            int t = __shfl_up(incl, o);
            if (tid >= o) incl += t;
        }
        base[tid] = incl - v;
    }
    __syncthreads();
    #pragma unroll
    for (int u = 0; u < 4; ++u) {
        int i = tile0 + tid + u * 256;
        if (i < N) perm[tile0 + base[deg[u]] + lrank[u]] = i;
    }
}

// ---------------- MFMA GEMM on packed inputs, head-major C writes ----------------

__device__ __forceinline__ void gll16(const f16* g, f16* l) {
#if __has_builtin(__builtin_amdgcn_global_load_lds)
    __builtin_amdgcn_global_load_lds((const __attribute__((address_space(1))) void*)g,
                                     (__attribute__((address_space(3))) void*)l, 16, 0, 0);
#else
    *(f16x8*)l = *(const f16x8*)g;
#endif
}

__global__ __launch_bounds__(256) void gemm16_packed(
    const f16* __restrict__ PA, int N, int K,
    const f16* __restrict__ PBl, const f16* __restrict__ PBr,
    f16* __restrict__ Cl, f16* __restrict__ Cr) {
    __shared__ f16 lds[2][2][8192];  // 64KB
    const int nblk = gridDim.x;
    int bid = blockIdx.x;
    int xcd = bid & 7, jj = bid >> 3;
    int nper = nblk >> 3, rem = nblk & 7;
    int slot = (xcd < rem) ? xcd * (nper + 1) + jj
                           : rem * (nper + 1) + (xcd - rem) * nper + jj;
    int R = slot >> 2, by = slot & 3;
    const f16* __restrict__ PB = (by >> 1) ? PBr : PBl;
    f16* __restrict__ C = (by >> 1) ? Cr : Cl;
    const int cb = by & 1;
    const int row0 = R * 128;
    const int col0 = cb * 128;
    const f16* Abase = PA + (size_t)R * 128 * K;
    const f16* Bbase = PB + (size_t)cb * 128 * K;
    const int t = threadIdx.x;
    const int lane = t & 63, wid = t >> 6;
    const int wr = (wid >> 1) * 64, wc = (wid & 1) * 64;
    const int lg = lane >> 4, lr = lane & 15;

    f32x4 acc[4][4];
    #pragma unroll
    for (int m = 0; m < 4; ++m)
        #pragma unroll
        for (int n = 0; n < 4; ++n) acc[m][n] = (f32x4){0.f, 0.f, 0.f, 0.f};

    auto stage = [&](int buf, int k0) {
        const f16* As = Abase + (size_t)k0 * 128 + t * 8;
        const f16* Bs = Bbase + (size_t)k0 * 128 + t * 8;
        f16* Al = &lds[buf][0][t * 8];
        f16* Bl = &lds[buf][1][t * 8];
        #pragma unroll
        for (int u = 0; u < 4; ++u) gll16(As + u * 2048, Al + u * 2048);
        #pragma unroll
        for (int u = 0; u < 4; ++u) gll16(Bs + u * 2048, Bl + u * 2048);
    };

    const int nk = K >> 6;
    stage(0, 0);
    asm volatile("s_waitcnt vmcnt(0)" ::: "memory");
    __syncthreads();
    for (int c = 0; c < nk; ++c) {
        if (c + 1 < nk) stage((c + 1) & 1, (c + 1) * 64);
        f16x8* Asp = (f16x8*)lds[c & 1][0];
        f16x8* Bsp = (f16x8*)lds[c & 1][1];
        #pragma unroll
        for (int s = 0; s < 2; ++s) {
            f16x8 af[4], bf[4];
            #pragma unroll
            for (int m = 0; m < 4; ++m) af[m] = Asp[(s * 4 + lg) * 128 + wr + m * 16 + lr];
            #pragma unroll
            for (int n = 0; n < 4; ++n) bf[n] = Bsp[(s * 4 + lg) * 128 + wc + n * 16 + lr];
            #pragma unroll
            for (int m = 0; m < 4; ++m)
                #pragma unroll
                for (int n = 0; n < 4; ++n)
                    acc[m][n] = __builtin_amdgcn_mfma_f32_16x16x32_f16(af[m], bf[n], acc[m][n], 0, 0, 0);
        }
        asm volatile("s_waitcnt vmcnt(0)" ::: "memory");
        __syncthreads();
    }
    // epilogue: head-major C [h][N][32]; col groups of 16 never cross a head boundary
    const size_t hs = (size_t)N * 32;
    #pragma unroll
    for (int m = 0; m < 4; ++m) {
        int row_b = row0 + wr + m * 16 + lg * 4;
        #pragma unroll
        for (int reg = 0; reg < 4; ++reg) {
            int row = row_b + reg;
            if (row < N) {
                #pragma unroll
                for (int n = 0; n < 4; ++n) {
                    int col = col0 + wc + n * 16 + lr;
                    C[hs * (col >> 5) + (size_t)row * 32 + (col & 31)] = (f16)acc[m][n][reg];
                }
            }
        }
    }
}

// ---------------- small GEMM layer 4 ----------------

__global__ __launch_bounds__(256) void gemm_small16(
    const f16* __restrict__ A, int N,
    const float* __restrict__ Wl, const float* __restrict__ Wr,
    float* __restrict__ Cl, float* __restrict__ Cr) {
    const int K = 256, M = 16;
    __shared__ float As[16][260];
    __shared__ float Ws[256 * 16];
    const float* __restrict__ W = (blockIdx.y == 0) ? Wl : Wr;
    float* __restrict__ C = (blockIdx.y == 0) ? Cl : Cr;
    int row0 = blockIdx.x * 16;
    int tid = threadIdx.x;
    {
        #pragma unroll
        for (int u = 0; u < 4; ++u)
            *(float4*)&Ws[tid * 16 + u * 4] = *(const float4*)(W + tid * 16 + u * 4);
        int r = tid >> 4;
        int c = (tid & 15) * 16;
        int row = row0 + r;
        if (row < N) {
            int R = row >> 7, rr = row & 127;
            const f16* base = A + ((size_t)(R * 32 + (c >> 3)) * 128 + rr) * 8;
            f16x8 v0 = *(const f16x8*)base;
            f16x8 v1 = *(const f16x8*)(base + 1024);
            #pragma unroll
            for (int j = 0; j < 8; ++j) {
                As[r][c + j] = (float)v0[j];
                As[r][c + 8 + j] = (float)v1[j];
            }
        } else {
            #pragma unroll
            for (int j = 0; j < 16; ++j) As[r][c + j] = 0.f;
        }
    }
    __syncthreads();
    int r = tid >> 4;
    int col = tid & 15;
    float acc = 0.f;
    #pragma unroll 8
    for (int k = 0; k < K; ++k) acc = fmaf(As[r][k], Ws[k * M + col], acc);
    int row = row0 + r;
    if (row < N) C[(size_t)row * M + col] = acc;
}

// ------- edge kernel: head-split (h=bid&7 -> XCD-local 3.2MB region), tile-sorted ----
// 4 lanes x f16x8 per (node,head) task, 64 tasks/block; perm is tile-local so all
// side-streams (xr, ss, PH) stay within the block's ~1K-node neighborhood.

__global__ __launch_bounds__(256) void edge_h8_sorted(
    const f16* __restrict__ xl, const f16* __restrict__ xr,
    const int* __restrict__ rp, const int* __restrict__ ss,
    const int* __restrict__ perm,
    const float* __restrict__ att, const float* __restrict__ bias,
    f16* __restrict__ hout, int N) {
    int bid = blockIdx.x;
    int h = bid & 7;
    int tile = bid >> 3;
    int tid = threadIdx.x;
    int task = tile * 64 + (tid >> 2);
    if (task >= N) return;
    int n = perm[task];
    int ll = tid & 3;  // dims h*32 + ll*8 .. +8
    const size_t hs = (size_t)N * 32;
    const f16* xlh = xl + hs * h;
    const int doff = h * 32 + ll * 8;
    f16x8 xrr = *(const f16x8*)(xr + hs * h + (size_t)n * 32 + ll * 8);
    float4 atlo = *(const float4*)(att + doff);
    float4 athi = *(const float4*)(att + doff + 4);
    f16x2 at01 = {(f16)atlo.x, (f16)atlo.y};
    f16x2 at23 = {(f16)atlo.z, (f16)atlo.w};
    f16x2 at45 = {(f16)athi.x, (f16)athi.y};
    f16x2 at67 = {(f16)athi.z, (f16)athi.w};
    const f16 ns = (f16)NEG_SLOPE;
    float m = -INFINITY, s = 0.f;
    f16x8 a = {0, 0, 0, 0, 0, 0, 0, 0};
    int beg = rp[n], end = rp[n + 1];
    int last = end - 1;
    const f16* xb = xlh + ll * 8;
    f16x8 r0 = *(const f16x8*)(xb + (size_t)ss[beg] * 32);
    f16x8 r1 = *(const f16x8*)(xb + (size_t)ss[min(beg + 1, last)] * 32);
    f16x8 r2 = *(const f16x8*)(xb + (size_t)ss[min(beg + 2, last)] * 32);
    f16x8 r3 = *(const f16x8*)(xb + (size_t)ss[min(beg + 3, last)] * 32);
    int j4 = ss[min(beg + 4, last)];
    int j5 = ss[min(beg + 5, last)];

    auto score = [&](const f16x8& cur) -> float {
        f16x8 g = cur + xrr;
        f16x8 gs = g * ns;
        f16x8 lk = __builtin_elementwise_max(g, gs);
#if __has_builtin(__builtin_amdgcn_fdot2)
        f16x2 l01 = __builtin_shufflevector(lk, lk, 0, 1);
        f16x2 l23 = __builtin_shufflevector(lk, lk, 2, 3);
        f16x2 l45 = __builtin_shufflevector(lk, lk, 4, 5);
        f16x2 l67 = __builtin_shufflevector(lk, lk, 6, 7);
        float p = __builtin_amdgcn_fdot2(l01, at01, 0.f, false);
        p = __builtin_amdgcn_fdot2(l23, at23, p, false);
        p = __builtin_amdgcn_fdot2(l45, at45, p, false);
        p = __builtin_amdgcn_fdot2(l67, at67, p, false);
#else
        float p = (float)lk[0] * atlo.x + (float)lk[1] * atlo.y +
                  (float)lk[2] * atlo.z + (float)lk[3] * atlo.w +
                  (float)lk[4] * athi.x + (float)lk[5] * athi.y +
                  (float)lk[6] * athi.z + (float)lk[7] * athi.w;
#endif
        return p;
    };

    int i = beg;
    for (; i + 1 < end; i += 2) {
        f16x8 c0 = r0, c1 = r1;
        r0 = r2; r1 = r3;
        r2 = *(const f16x8*)(xb + (size_t)j4 * 32);
        r3 = *(const f16x8*)(xb + (size_t)j5 * 32);
        j4 = ss[min(i + 6, last)];
        j5 = ss[min(i + 7, last)];
        float p0 = score(c0);
        float p1 = score(c1);
        p0 += __shfl_xor(p0, 1);
        p1 += __shfl_xor(p1, 1);
        p0 += __shfl_xor(p0, 2);
        p1 += __shfl_xor(p1, 2);  // 4-lane task reduce
        float d0 = p0 - m, d1 = p1 - m;
        if (__any(fmaxf(d0, d1) > 4.f)) {
            float mn = fmaxf(m, fmaxf(p0, p1));
            float cf = __expf(m - mn);  // exp(-inf)=0 handles init
            s *= cf;
            f16 cfh = (f16)cf;
            a = a * (f16x8){cfh, cfh, cfh, cfh, cfh, cfh, cfh, cfh};
            m = mn;
            d0 = p0 - m; d1 = p1 - m;
        }
        float e0 = __expf(d0);
        float e1 = __expf(d1);
        s += e0 + e1;
        f16 e0h = (f16)e0, e1h = (f16)e1;
        f16x8 e0v = {e0h, e0h, e0h, e0h, e0h, e0h, e0h, e0h};
        f16x8 e1v = {e1h, e1h, e1h, e1h, e1h, e1h, e1h, e1h};
#if __has_builtin(__builtin_elementwise_fma)
        a = __builtin_elementwise_fma(c0, e0v, a);
        a = __builtin_elementwise_fma(c1, e1v, a);
#else
        a = a + c0 * e0v + c1 * e1v;
#endif
    }
    if (i < end) {  // odd tail
        f16x8 c0 = r0;
        float p0 = score(c0);
        p0 += __shfl_xor(p0, 1);
        p0 += __shfl_xor(p0, 2);
        float d0 = p0 - m;
        if (__any(d0 > 4.f)) {
            float mn = fmaxf(m, p0);
            float cf = __expf(m - mn);
            s *= cf;
            f16 cfh = (f16)cf;
            a = a * (f16x8){cfh, cfh, cfh, cfh, cfh, cfh, cfh, cfh};
            m = mn;
            d0 = p0 - m;
        }
        float e0 = __expf(d0);
        s += e0;
        f16 e0h = (f16)e0;
        f16x8 e0v = {e0h, e0h, e0h, e0h, e0h, e0h, e0h, e0h};
#if __has_builtin(__builtin_elementwise_fma)
        a = __builtin_elementwise_fma(c0, e0v, a);
#else
        a = a + c0 * e0v;
#endif
    }
    float inv = 1.f / (s + 1e-16f);
    float4 blo = *(const float4*)(bias + doff);
    float4 bhi = *(const float4*)(bias + doff + 4);
    float o[8];
    o[0] = (float)a[0] * inv + blo.x; o[1] = (float)a[1] * inv + blo.y;
    o[2] = (float)a[2] * inv + blo.z; o[3] = (float)a[3] * inv + blo.w;
    o[4] = (float)a[4] * inv + bhi.x; o[5] = (float)a[5] * inv + bhi.y;
    o[6] = (float)a[6] * inv + bhi.z; o[7] = (float)a[7] * inv + bhi.w;
    f16x8 ov;
    #pragma unroll
    for (int j = 0; j < 8; ++j) {
        float e = o[j] > 0.f ? o[j] : __expf(o[j]) - 1.f;  // elu
        ov[j] = (f16)e;
    }
    // packed PH write: k-range h*32+ll*8 -> chunk 4h+ll, contiguous f16x8
    *(f16x8*)(hout + ((size_t)((n >> 7) * 32 + 4 * h + ll) * 128 + (n & 127)) * 8) = ov;
}

// ---------------- edge kernel layer 4: tile-sorted, four nodes/wave ----------------

__global__ __launch_bounds__(256) void edge_h1_kernel(
    const float* __restrict__ xl, const float* __restrict__ xr,
    const int* __restrict__ rp, const int* __restrict__ ss,
    const int* __restrict__ perm,
    const float* __restrict__ att, const float* __restrict__ bias,
    float* __restrict__ out, int N) {
    int tid = threadIdx.x;
    int grp = tid >> 4;
    int gl = tid & 15;
    int task = blockIdx.x * 16 + grp;
    if (task >= N) return;
    int n = perm[task];
    float xrv = xr[(size_t)n * 16 + gl];
    float attv = att[gl];
    float bv = bias[gl];
    float m = -INFINITY, s = 0.f, acc = 0.f;
    int beg = rp[n], end = rp[n + 1], last = end - 1;
    const float* xb = xl + gl;
    float x0 = xb[(size_t)ss[beg] * 16];
    float x1 = xb[(size_t)ss[min(beg + 1, last)] * 16];
    float x2 = xb[(size_t)ss[min(beg + 2, last)] * 16];
    float x3 = xb[(size_t)ss[min(beg + 3, last)] * 16];
    int j4 = ss[min(beg + 4, last)];
    int j5 = ss[min(beg + 5, last)];
    int i = beg;
    for (; i + 1 < end; i += 2) {
        float c0 = x0, c1 = x1;
        x0 = x2; x1 = x3;
        x2 = xb[(size_t)j4 * 16];
        x3 = xb[(size_t)j5 * 16];
        j4 = ss[min(i + 6, last)];
        j5 = ss[min(i + 7, last)];
        float g0 = c0 + xrv, g1 = c1 + xrv;
        float p0 = attv * fmaxf(g0, NEG_SLOPE * g0);
        float p1 = attv * fmaxf(g1, NEG_SLOPE * g1);
        p0 += __shfl_xor(p0, 1); p1 += __shfl_xor(p1, 1);
        p0 += __shfl_xor(p0, 2); p1 += __shfl_xor(p1, 2);
        p0 += __shfl_xor(p0, 4); p1 += __shfl_xor(p1, 4);
        p0 += __shfl_xor(p0, 8); p1 += __shfl_xor(p1, 8);
        float d0 = p0 - m, d1 = p1 - m;
        if (__any(fmaxf(d0, d1) > 8.f)) {
            float mn = fmaxf(m, fmaxf(p0, p1));
            float cf = __expf(m - mn);
            s *= cf; acc *= cf;
            m = mn;
            d0 = p0 - m; d1 = p1 - m;
        }
        float e0 = __expf(d0), e1 = __expf(d1);
        s += e0 + e1;
        acc = fmaf(e1, c1, fmaf(e0, c0, acc));
    }
    if (i < end) {
        float c0 = x0;
        float g0 = c0 + xrv;
        float p0 = attv * fmaxf(g0, NEG_SLOPE * g0);
        p0 += __shfl_xor(p0, 1);
        p0 += __shfl_xor(p0, 2);
        p0 += __shfl_xor(p0, 4);
        p0 += __shfl_xor(p0, 8);
        float d0 = p0 - m;
        if (__any(d0 > 8.f)) {
            float mn = fmaxf(m, p0);
            float cf = __expf(m - mn);
            s *= cf; acc *= cf;
            m = mn;
            d0 = p0 - m;
        }
        float e0 = __expf(d0);
        s += e0;
        acc = fmaf(e0, c0, acc);
    }
    float v = acc / (s + 1e-16f) + bv;
    float mx = v;
    mx = fmaxf(mx, __shfl_xor(mx, 1));
    mx = fmaxf(mx, __shfl_xor(mx, 2));
    mx = fmaxf(mx, __shfl_xor(mx, 4));
    mx = fmaxf(mx, __shfl_xor(mx, 8));
    float ex = __expf(v - mx);
    float se = ex;
    se += __shfl_xor(se, 1);
    se += __shfl_xor(se, 2);
    se += __shfl_xor(se, 4);
    se += __shfl_xor(se, 8);
    out[(size_t)n * 16 + gl] = v - mx - __logf(se);
}

// ---------------- launch ----------------

extern "C" void kernel_launch(void* const* d_in, const int* in_sizes, int n_in,
                              void* d_out, int out_size, void* d_ws, size_t ws_size,
                              hipStream_t stream) {
    const float* x    = (const float*)d_in[0];
    const int*   ei   = (const int*)d_in[1];
    const float* Wl1  = (const float*)d_in[2];
    const float* Wr1  = (const float*)d_in[3];
    const float* att1 = (const float*)d_in[4];
    const float* b1   = (const float*)d_in[5];
    const float* Wl2  = (const float*)d_in[6];
    const float* Wr2  = (const float*)d_in[7];
    const float* att2 = (const float*)d_in[8];
    const float* b2   = (const float*)d_in[9];
    const float* Wl3  = (const float*)d_in[10];
    const float* Wr3  = (const float*)d_in[11];
    const float* att3 = (const float*)d_in[12];
    const float* b3   = (const float*)d_in[13];
    const float* Wl4  = (const float*)d_in[14];
    const float* Wr4  = (const float*)d_in[15];
    const float* att4 = (const float*)d_in[16];
    const float* b4   = (const float*)d_in[17];

    const int N = in_sizes[0] / 128;
    const int E = in_sizes[1] / 2;
    const int* src = ei;
    const int* dst = ei + E;
    const int Etot = E + N;
    const int ntile = idiv(N, 128);

    char* wsb = (char*)d_ws;
    size_t off = 0;
    auto alloc = [&](size_t bytes) -> void* {
        void* p = wsb + off;
        off += (bytes + 255) & ~(size_t)255;
        return p;
    };
    f16*   PX   = (f16*)alloc((size_t)ntile * 128 * 128 * 2);
    f16*   PH   = (f16*)alloc((size_t)ntile * 128 * 256 * 2);
    f16*   xl16 = (f16*)alloc((size_t)N * 256 * 2);   // head-major [8][N][32]
    f16*   xr16 = (f16*)alloc((size_t)N * 256 * 2);   // head-major [8][N][32]
    float* xl4  = (float*)alloc((size_t)N * 16 * 4);
    float* xr4  = (float*)alloc((size_t)N * 16 * 4);
    f16*   PB1l = (f16*)alloc((size_t)256 * 128 * 2);
    f16*   PB1r = (f16*)alloc((size_t)256 * 128 * 2);
    f16*   PB2l = (f16*)alloc((size_t)256 * 256 * 2);
    f16*   PB2r = (f16*)alloc((size_t)256 * 256 * 2);
    f16*   PB3l = (f16*)alloc((size_t)256 * 256 * 2);
    f16*   PB3r = (f16*)alloc((size_t)256 * 256 * 2);
    int*   cnt  = (int*)alloc((size_t)N * 4);
    int*   wof  = (int*)alloc((size_t)N * 4);
    int*   rp   = (int*)alloc((size_t)(N + 1) * 4);
    int*   ss   = (int*)alloc((size_t)Etot * 4);
    int*   bsum = (int*)alloc((size_t)idiv(N, 1024) * 4);
    int*   perm = (int*)alloc((size_t)N * 4);

    // conversions
    conv_x_packed<<<ntile, 256, 0, stream>>>(x, PX, N);
    convT_all<<<dim3(8, 8, 6), 256, 0, stream>>>(Wl1, Wr1, Wl2, Wr2, Wl3, Wr3,
                                                 PB1l, PB1r, PB2l, PB2r, PB3l, PB3r);

    // CSR build
    hipMemsetAsync(cnt, 0, (size_t)N * 4, stream);
    hist_kernel<<<idiv(Etot, 256), 256, 0, stream>>>(dst, E, N, cnt);
    const int nb = idiv(N, 1024);
    scanA<<<nb, 256, 0, stream>>>(cnt, bsum, N);
    scanB<<<1, 256, 0, stream>>>(bsum, nb);
    scanC<<<nb, 256, 0, stream>>>(cnt, bsum, rp, wof, N);
    scatter_kernel<<<idiv(Etot, 256), 256, 0, stream>>>(src, dst, E, N, wof, ss);
    // tile-local degree sort (locality-preserving)
    tile_sort<<<nb, 256, 0, stream>>>(rp, N, perm);

    const int nblk = ntile * 4;
    const int egrid = idiv(N, 64) * 8;
    // layer 1 (K=128)
    gemm16_packed<<<nblk, 256, 0, stream>>>(PX, N, 128, PB1l, PB1r, xl16, xr16);
    edge_h8_sorted<<<egrid, 256, 0, stream>>>(xl16, xr16, rp, ss, perm, att1, b1, PH, N);
    // layer 2
    gemm16_packed<<<nblk, 256, 0, stream>>>(PH, N, 256, PB2l, PB2r, xl16, xr16);
    edge_h8_sorted<<<egrid, 256, 0, stream>>>(xl16, xr16, rp, ss, perm, att2, b2, PH, N);
    // layer 3
    gemm16_packed<<<nblk, 256, 0, stream>>>(PH, N, 256, PB3l, PB3r, xl16, xr16);
    edge_h8_sorted<<<egrid, 256, 0, stream>>>(xl16, xr16, rp, ss, perm, att3, b3, PH, N);
    // layer 4 (M=16) + fused log_softmax
    gemm_small16<<<dim3(idiv(N, 16), 2), 256, 0, stream>>>(PH, N, Wl4, Wr4, xl4, xr4);
    edge_h1_kernel<<<idiv(N, 16), 256, 0, stream>>>(xl4, xr4, rp, ss, perm, att4, b4,
                                                    (float*)d_out, N);
}

// Round 11
// 437.416 us; speedup vs baseline: 1.2024x; 1.1367x over previous
//
#include <hip/hip_runtime.h>
#include <math.h>

#define NEG_SLOPE 0.2f

typedef _Float16 f16;
typedef _Float16 f16x2 __attribute__((ext_vector_type(2)));
typedef _Float16 f16x4 __attribute__((ext_vector_type(4)));
typedef _Float16 f16x8 __attribute__((ext_vector_type(8)));
typedef float f32x4 __attribute__((ext_vector_type(4)));

static inline int idiv(int a, int b) { return (a + b - 1) / b; }

// Packed activation layout for GEMM-A/B (fragment-major, matches LDS image):
//   elem(row, k) at ((row>>7)*(K>>3) + (k>>3))*128*8 + (row&127)*8 + (k&7)
// Head-major activation layout for edge phase: xl/xr stored [h][N][32] f16,
// so each head's gather region is 3.2MB -> fits one XCD's 4MB L2.
// NO scheduling permutation: rounds 5/8/9 proved any perm costs more in lost
// write/read coalescing than it saves in degree uniformity.

// ---------------- conversions ----------------

__global__ __launch_bounds__(256) void conv_x_packed(const float* __restrict__ x,
                                                     f16* __restrict__ pa, int N) {
    int R = blockIdx.x;
    #pragma unroll
    for (int u = 0; u < 8; ++u) {
        int c = threadIdx.x + u * 256;
        int g = c >> 7, r = c & 127;
        int row = R * 128 + r;
        f16x8 v;
        if (row < N) {
            float4 a = *(const float4*)(x + (size_t)row * 128 + g * 8);
            float4 b = *(const float4*)(x + (size_t)row * 128 + g * 8 + 4);
            v = (f16x8){(f16)a.x, (f16)a.y, (f16)a.z, (f16)a.w,
                        (f16)b.x, (f16)b.y, (f16)b.z, (f16)b.w};
        } else {
            v = (f16x8){0, 0, 0, 0, 0, 0, 0, 0};
        }
        *(f16x8*)(pa + ((size_t)(R * 16 + g) * 128 + r) * 8) = v;
    }
}

__global__ __launch_bounds__(256) void convT_all(
    const float* __restrict__ W1l, const float* __restrict__ W1r,
    const float* __restrict__ W2l, const float* __restrict__ W2r,
    const float* __restrict__ W3l, const float* __restrict__ W3r,
    f16* __restrict__ P1l, f16* __restrict__ P1r,
    f16* __restrict__ P2l, f16* __restrict__ P2r,
    f16* __restrict__ P3l, f16* __restrict__ P3r) {
    __shared__ float tbl[32][33];
    const float* W;
    f16* P;
    int K;
    switch (blockIdx.z) {
        case 0: W = W1l; P = P1l; K = 128; break;
        case 1: W = W1r; P = P1r; K = 128; break;
        case 2: W = W2l; P = P2l; K = 256; break;
        case 3: W = W2r; P = P2r; K = 256; break;
        case 4: W = W3l; P = P3l; K = 256; break;
        default: W = W3r; P = P3r; K = 256; break;
    }
    int bk = blockIdx.x * 32, bc = blockIdx.y * 32;
    if (bk >= K) return;
    int tx = threadIdx.x & 31, ty = threadIdx.x >> 5;
    #pragma unroll
    for (int i = 0; i < 32; i += 8)
        tbl[ty + i][tx] = W[(size_t)(bk + ty + i) * 256 + bc + tx];
    __syncthreads();
    if (threadIdx.x < 128) {
        int cl = threadIdx.x & 31;
        int gl = threadIdx.x >> 5;
        int col = bc + cl;
        int g = (bk >> 3) + gl;
        f16x8 v;
        #pragma unroll
        for (int j = 0; j < 8; ++j) v[j] = (f16)tbl[gl * 8 + j][cl];
        *(f16x8*)(P + ((size_t)((col >> 7) * (K >> 3) + g) * 128 + (col & 127)) * 8) = v;
    }
}

// ---------------- CSR build ----------------

__global__ void hist_kernel(const int* __restrict__ dst, int E, int N, int* __restrict__ cnt) {
    int i = blockIdx.x * blockDim.x + threadIdx.x;
    if (i >= E + N) return;
    int d = (i < E) ? dst[i] : (i - E);
    atomicAdd(&cnt[d], 1);
}

__global__ __launch_bounds__(256) void scanA(const int* __restrict__ cnt,
                                             int* __restrict__ bsum, int N) {
    __shared__ int ws[4];
    int tid = threadIdx.x, lane = tid & 63, wid = tid >> 6;
    int i0 = blockIdx.x * 1024 + tid * 4;
    int s = 0;
    if (i0 + 3 < N) {
        int4 v = *(const int4*)(cnt + i0);
        s = v.x + v.y + v.z + v.w;
    } else {
        for (int j = 0; j < 4; ++j)
            if (i0 + j < N) s += cnt[i0 + j];
    }
    #pragma unroll
    for (int o = 1; o < 64; o <<= 1) s += __shfl_xor(s, o);
    if (lane == 0) ws[wid] = s;
    __syncthreads();
    if (tid == 0) bsum[blockIdx.x] = ws[0] + ws[1] + ws[2] + ws[3];
}

__global__ __launch_bounds__(256) void scanB(int* __restrict__ bsum, int nb) {
    __shared__ int ws[4];
    int tid = threadIdx.x, lane = tid & 63, wid = tid >> 6;
    int v = (tid < nb) ? bsum[tid] : 0;
    int incl = v;
    #pragma unroll
    for (int o = 1; o < 64; o <<= 1) {
        int t = __shfl_up(incl, o);
        if (lane >= o) incl += t;
    }
    if (lane == 63) ws[wid] = incl;
    __syncthreads();
    int add = 0;
    for (int w = 0; w < wid; ++w) add += ws[w];
    if (tid < nb) bsum[tid] = add + incl - v;
}

__global__ __launch_bounds__(256) void scanC(const int* __restrict__ cnt,
                                             const int* __restrict__ bsum,
                                             int* __restrict__ rp, int* __restrict__ wofs, int N) {
    __shared__ int ws[4];
    __shared__ int base_s;
    int tid = threadIdx.x, lane = tid & 63, wid = tid >> 6;
    int i0 = blockIdx.x * 1024 + tid * 4;
    int v0 = (i0 + 0 < N) ? cnt[i0 + 0] : 0;
    int v1 = (i0 + 1 < N) ? cnt[i0 + 1] : 0;
    int v2 = (i0 + 2 < N) ? cnt[i0 + 2] : 0;
    int v3 = (i0 + 3 < N) ? cnt[i0 + 3] : 0;
    int t4 = v0 + v1 + v2 + v3;
    int incl = t4;
    #pragma unroll
    for (int o = 1; o < 64; o <<= 1) {
        int t = __shfl_up(incl, o);
        if (lane >= o) incl += t;
    }
    if (lane == 63) ws[wid] = incl;
    if (tid == 0) base_s = bsum[blockIdx.x];
    __syncthreads();
    int wadd = 0;
    for (int w = 0; w < wid; ++w) wadd += ws[w];
    int pre = base_s + wadd + incl - t4;
    int p1 = pre + v0, p2 = p1 + v1, p3 = p2 + v2, p4 = p3 + v3;
    if (i0 + 0 < N) { wofs[i0 + 0] = pre; rp[i0 + 1] = p1; }
    if (i0 + 1 < N) { wofs[i0 + 1] = p1;  rp[i0 + 2] = p2; }
    if (i0 + 2 < N) { wofs[i0 + 2] = p2;  rp[i0 + 3] = p3; }
    if (i0 + 3 < N) { wofs[i0 + 3] = p3;  rp[i0 + 4] = p4; }
    if (blockIdx.x == 0 && tid == 0) rp[0] = 0;
}

__global__ void scatter_kernel(const int* __restrict__ src, const int* __restrict__ dst,
                               int E, int N, int* __restrict__ wofs, int* __restrict__ sorted_src) {
    int i = blockIdx.x * blockDim.x + threadIdx.x;
    if (i >= E + N) return;
    int d, s;
    if (i < E) { d = dst[i]; s = src[i]; } else { d = i - E; s = d; }
    int pos = atomicAdd(&wofs[d], 1);
    sorted_src[pos] = s;
}

// ---------------- MFMA GEMM on packed inputs, head-major C writes ----------------

__device__ __forceinline__ void gll16(const f16* g, f16* l) {
#if __has_builtin(__builtin_amdgcn_global_load_lds)
    __builtin_amdgcn_global_load_lds((const __attribute__((address_space(1))) void*)g,
                                     (__attribute__((address_space(3))) void*)l, 16, 0, 0);
#else
    *(f16x8*)l = *(const f16x8*)g;
#endif
}

__global__ __launch_bounds__(256) void gemm16_packed(
    const f16* __restrict__ PA, int N, int K,
    const f16* __restrict__ PBl, const f16* __restrict__ PBr,
    f16* __restrict__ Cl, f16* __restrict__ Cr) {
    __shared__ f16 lds[2][2][8192];  // 64KB
    const int nblk = gridDim.x;
    int bid = blockIdx.x;
    int xcd = bid & 7, jj = bid >> 3;
    int nper = nblk >> 3, rem = nblk & 7;
    int slot = (xcd < rem) ? xcd * (nper + 1) + jj
                           : rem * (nper + 1) + (xcd - rem) * nper + jj;
    int R = slot >> 2, by = slot & 3;
    const f16* __restrict__ PB = (by >> 1) ? PBr : PBl;
    f16* __restrict__ C = (by >> 1) ? Cr : Cl;
    const int cb = by & 1;
    const int row0 = R * 128;
    const int col0 = cb * 128;
    const f16* Abase = PA + (size_t)R * 128 * K;
    const f16* Bbase = PB + (size_t)cb * 128 * K;
    const int t = threadIdx.x;
    const int lane = t & 63, wid = t >> 6;
    const int wr = (wid >> 1) * 64, wc = (wid & 1) * 64;
    const int lg = lane >> 4, lr = lane & 15;

    f32x4 acc[4][4];
    #pragma unroll
    for (int m = 0; m < 4; ++m)
        #pragma unroll
        for (int n = 0; n < 4; ++n) acc[m][n] = (f32x4){0.f, 0.f, 0.f, 0.f};

    auto stage = [&](int buf, int k0) {
        const f16* As = Abase + (size_t)k0 * 128 + t * 8;
        const f16* Bs = Bbase + (size_t)k0 * 128 + t * 8;
        f16* Al = &lds[buf][0][t * 8];
        f16* Bl = &lds[buf][1][t * 8];
        #pragma unroll
        for (int u = 0; u < 4; ++u) gll16(As + u * 2048, Al + u * 2048);
        #pragma unroll
        for (int u = 0; u < 4; ++u) gll16(Bs + u * 2048, Bl + u * 2048);
    };

    const int nk = K >> 6;
    stage(0, 0);
    asm volatile("s_waitcnt vmcnt(0)" ::: "memory");
    __syncthreads();
    for (int c = 0; c < nk; ++c) {
        if (c + 1 < nk) stage((c + 1) & 1, (c + 1) * 64);
        f16x8* Asp = (f16x8*)lds[c & 1][0];
        f16x8* Bsp = (f16x8*)lds[c & 1][1];
        #pragma unroll
        for (int s = 0; s < 2; ++s) {
            f16x8 af[4], bf[4];
            #pragma unroll
            for (int m = 0; m < 4; ++m) af[m] = Asp[(s * 4 + lg) * 128 + wr + m * 16 + lr];
            #pragma unroll
            for (int n = 0; n < 4; ++n) bf[n] = Bsp[(s * 4 + lg) * 128 + wc + n * 16 + lr];
            #pragma unroll
            for (int m = 0; m < 4; ++m)
                #pragma unroll
                for (int n = 0; n < 4; ++n)
                    acc[m][n] = __builtin_amdgcn_mfma_f32_16x16x32_f16(af[m], bf[n], acc[m][n], 0, 0, 0);
        }
        asm volatile("s_waitcnt vmcnt(0)" ::: "memory");
        __syncthreads();
    }
    // epilogue: head-major C [h][N][32]; col groups of 16 never cross a head boundary
    const size_t hs = (size_t)N * 32;
    #pragma unroll
    for (int m = 0; m < 4; ++m) {
        int row_b = row0 + wr + m * 16 + lg * 4;
        #pragma unroll
        for (int reg = 0; reg < 4; ++reg) {
            int row = row_b + reg;
            if (row < N) {
                #pragma unroll
                for (int n = 0; n < 4; ++n) {
                    int col = col0 + wc + n * 16 + lr;
                    C[hs * (col >> 5) + (size_t)row * 32 + (col & 31)] = (f16)acc[m][n][reg];
                }
            }
        }
    }
}

// ---------------- small GEMM layer 4 ----------------

__global__ __launch_bounds__(256) void gemm_small16(
    const f16* __restrict__ A, int N,
    const float* __restrict__ Wl, const float* __restrict__ Wr,
    float* __restrict__ Cl, float* __restrict__ Cr) {
    const int K = 256, M = 16;
    __shared__ float As[16][260];
    __shared__ float Ws[256 * 16];
    const float* __restrict__ W = (blockIdx.y == 0) ? Wl : Wr;
    float* __restrict__ C = (blockIdx.y == 0) ? Cl : Cr;
    int row0 = blockIdx.x * 16;
    int tid = threadIdx.x;
    {
        #pragma unroll
        for (int u = 0; u < 4; ++u)
            *(float4*)&Ws[tid * 16 + u * 4] = *(const float4*)(W + tid * 16 + u * 4);
        int r = tid >> 4;
        int c = (tid & 15) * 16;
        int row = row0 + r;
        if (row < N) {
            int R = row >> 7, rr = row & 127;
            const f16* base = A + ((size_t)(R * 32 + (c >> 3)) * 128 + rr) * 8;
            f16x8 v0 = *(const f16x8*)base;
            f16x8 v1 = *(const f16x8*)(base + 1024);
            #pragma unroll
            for (int j = 0; j < 8; ++j) {
                As[r][c + j] = (float)v0[j];
                As[r][c + 8 + j] = (float)v1[j];
            }
        } else {
            #pragma unroll
            for (int j = 0; j < 16; ++j) As[r][c + j] = 0.f;
        }
    }
    __syncthreads();
    int r = tid >> 4;
    int col = tid & 15;
    float acc = 0.f;
    #pragma unroll 8
    for (int k = 0; k < K; ++k) acc = fmaf(As[r][k], Ws[k * M + col], acc);
    int row = row0 + r;
    if (row < N) C[(size_t)row * M + col] = acc;
}

// ------- edge kernel: head-split (h=bid&7 -> XCD-local 3.2MB region), NATURAL order ----
// 4 lanes x f16x8 per (node,head) task, 64 consecutive nodes/block: xr reads, ss
// stream and PH writes fully coalesced; xl gathers hit the L2-resident head region.

__global__ __launch_bounds__(256) void edge_h8_ns(
    const f16* __restrict__ xl, const f16* __restrict__ xr,
    const int* __restrict__ rp, const int* __restrict__ ss,
    const float* __restrict__ att, const float* __restrict__ bias,
    f16* __restrict__ hout, int N) {
    int bid = blockIdx.x;
    int h = bid & 7;
    int tile = bid >> 3;
    int tid = threadIdx.x;
    int n = tile * 64 + (tid >> 2);
    if (n >= N) return;
    int ll = tid & 3;  // dims h*32 + ll*8 .. +8
    const size_t hs = (size_t)N * 32;
    const f16* xlh = xl + hs * h;
    const int doff = h * 32 + ll * 8;
    f16x8 xrr = *(const f16x8*)(xr + hs * h + (size_t)n * 32 + ll * 8);
    float4 atlo = *(const float4*)(att + doff);
    float4 athi = *(const float4*)(att + doff + 4);
    f16x2 at01 = {(f16)atlo.x, (f16)atlo.y};
    f16x2 at23 = {(f16)atlo.z, (f16)atlo.w};
    f16x2 at45 = {(f16)athi.x, (f16)athi.y};
    f16x2 at67 = {(f16)athi.z, (f16)athi.w};
    const f16 ns = (f16)NEG_SLOPE;
    float m = -INFINITY, s = 0.f;
    f16x8 a = {0, 0, 0, 0, 0, 0, 0, 0};
    int beg = rp[n], end = rp[n + 1];
    int last = end - 1;
    const f16* xb = xlh + ll * 8;
    f16x8 r0 = *(const f16x8*)(xb + (size_t)ss[beg] * 32);
    f16x8 r1 = *(const f16x8*)(xb + (size_t)ss[min(beg + 1, last)] * 32);
    f16x8 r2 = *(const f16x8*)(xb + (size_t)ss[min(beg + 2, last)] * 32);
    f16x8 r3 = *(const f16x8*)(xb + (size_t)ss[min(beg + 3, last)] * 32);
    int j4 = ss[min(beg + 4, last)];
    int j5 = ss[min(beg + 5, last)];

    auto score = [&](const f16x8& cur) -> float {
        f16x8 g = cur + xrr;
        f16x8 gs = g * ns;
        f16x8 lk = __builtin_elementwise_max(g, gs);
#if __has_builtin(__builtin_amdgcn_fdot2)
        f16x2 l01 = __builtin_shufflevector(lk, lk, 0, 1);
        f16x2 l23 = __builtin_shufflevector(lk, lk, 2, 3);
        f16x2 l45 = __builtin_shufflevector(lk, lk, 4, 5);
        f16x2 l67 = __builtin_shufflevector(lk, lk, 6, 7);
        float p = __builtin_amdgcn_fdot2(l01, at01, 0.f, false);
        p = __builtin_amdgcn_fdot2(l23, at23, p, false);
        p = __builtin_amdgcn_fdot2(l45, at45, p, false);
        p = __builtin_amdgcn_fdot2(l67, at67, p, false);
#else
        float p = (float)lk[0] * atlo.x + (float)lk[1] * atlo.y +
                  (float)lk[2] * atlo.z + (float)lk[3] * atlo.w +
                  (float)lk[4] * athi.x + (float)lk[5] * athi.y +
                  (float)lk[6] * athi.z + (float)lk[7] * athi.w;
#endif
        return p;
    };

    int i = beg;
    for (; i + 1 < end; i += 2) {
        f16x8 c0 = r0, c1 = r1;
        r0 = r2; r1 = r3;
        r2 = *(const f16x8*)(xb + (size_t)j4 * 32);
        r3 = *(const f16x8*)(xb + (size_t)j5 * 32);
        j4 = ss[min(i + 6, last)];
        j5 = ss[min(i + 7, last)];
        float p0 = score(c0);
        float p1 = score(c1);
        p0 += __shfl_xor(p0, 1);
        p1 += __shfl_xor(p1, 1);
        p0 += __shfl_xor(p0, 2);
        p1 += __shfl_xor(p1, 2);  // 4-lane task reduce
        float d0 = p0 - m, d1 = p1 - m;
        if (__any(fmaxf(d0, d1) > 4.f)) {
            float mn = fmaxf(m, fmaxf(p0, p1));
            float cf = __expf(m - mn);  // exp(-inf)=0 handles init
            s *= cf;
            f16 cfh = (f16)cf;
            a = a * (f16x8){cfh, cfh, cfh, cfh, cfh, cfh, cfh, cfh};
            m = mn;
            d0 = p0 - m; d1 = p1 - m;
        }
        float e0 = __expf(d0);
        float e1 = __expf(d1);
        s += e0 + e1;
        f16 e0h = (f16)e0, e1h = (f16)e1;
        f16x8 e0v = {e0h, e0h, e0h, e0h, e0h, e0h, e0h, e0h};
        f16x8 e1v = {e1h, e1h, e1h, e1h, e1h, e1h, e1h, e1h};
#if __has_builtin(__builtin_elementwise_fma)
        a = __builtin_elementwise_fma(c0, e0v, a);
        a = __builtin_elementwise_fma(c1, e1v, a);
#else
        a = a + c0 * e0v + c1 * e1v;
#endif
    }
    if (i < end) {  // odd tail
        f16x8 c0 = r0;
        float p0 = score(c0);
        p0 += __shfl_xor(p0, 1);
        p0 += __shfl_xor(p0, 2);
        float d0 = p0 - m;
        if (__any(d0 > 4.f)) {
            float mn = fmaxf(m, p0);
            float cf = __expf(m - mn);
            s *= cf;
            f16 cfh = (f16)cf;
            a = a * (f16x8){cfh, cfh, cfh, cfh, cfh, cfh, cfh, cfh};
            m = mn;
            d0 = p0 - m;
        }
        float e0 = __expf(d0);
        s += e0;
        f16 e0h = (f16)e0;
        f16x8 e0v = {e0h, e0h, e0h, e0h, e0h, e0h, e0h, e0h};
#if __has_builtin(__builtin_elementwise_fma)
        a = __builtin_elementwise_fma(c0, e0v, a);
#else
        a = a + c0 * e0v;
#endif
    }
    float inv = 1.f / (s + 1e-16f);
    float4 blo = *(const float4*)(bias + doff);
    float4 bhi = *(const float4*)(bias + doff + 4);
    float o[8];
    o[0] = (float)a[0] * inv + blo.x; o[1] = (float)a[1] * inv + blo.y;
    o[2] = (float)a[2] * inv + blo.z; o[3] = (float)a[3] * inv + blo.w;
    o[4] = (float)a[4] * inv + bhi.x; o[5] = (float)a[5] * inv + bhi.y;
    o[6] = (float)a[6] * inv + bhi.z; o[7] = (float)a[7] * inv + bhi.w;
    f16x8 ov;
    #pragma unroll
    for (int j = 0; j < 8; ++j) {
        float e = o[j] > 0.f ? o[j] : __expf(o[j]) - 1.f;  // elu
        ov[j] = (f16)e;
    }
    // packed PH write: k-range h*32+ll*8 -> chunk 4h+ll, contiguous f16x8
    *(f16x8*)(hout + ((size_t)((n >> 7) * 32 + 4 * h + ll) * 128 + (n & 127)) * 8) = ov;
}

// ---------------- edge kernel layer 4: natural order, four nodes/wave ----------------

__global__ __launch_bounds__(256) void edge_h1_kernel(
    const float* __restrict__ xl, const float* __restrict__ xr,
    const int* __restrict__ rp, const int* __restrict__ ss,
    const float* __restrict__ att, const float* __restrict__ bias,
    float* __restrict__ out, int N) {
    int tid = threadIdx.x;
    int grp = tid >> 4;
    int gl = tid & 15;
    int n = blockIdx.x * 16 + grp;
    if (n >= N) return;
    float xrv = xr[(size_t)n * 16 + gl];
    float attv = att[gl];
    float bv = bias[gl];
    float m = -INFINITY, s = 0.f, acc = 0.f;
    int beg = rp[n], end = rp[n + 1], last = end - 1;
    const float* xb = xl + gl;
    float x0 = xb[(size_t)ss[beg] * 16];
    float x1 = xb[(size_t)ss[min(beg + 1, last)] * 16];
    float x2 = xb[(size_t)ss[min(beg + 2, last)] * 16];
    float x3 = xb[(size_t)ss[min(beg + 3, last)] * 16];
    int j4 = ss[min(beg + 4, last)];
    int j5 = ss[min(beg + 5, last)];
    int i = beg;
    for (; i + 1 < end; i += 2) {
        float c0 = x0, c1 = x1;
        x0 = x2; x1 = x3;
        x2 = xb[(size_t)j4 * 16];
        x3 = xb[(size_t)j5 * 16];
        j4 = ss[min(i + 6, last)];
        j5 = ss[min(i + 7, last)];
        float g0 = c0 + xrv, g1 = c1 + xrv;
        float p0 = attv * fmaxf(g0, NEG_SLOPE * g0);
        float p1 = attv * fmaxf(g1, NEG_SLOPE * g1);
        p0 += __shfl_xor(p0, 1); p1 += __shfl_xor(p1, 1);
        p0 += __shfl_xor(p0, 2); p1 += __shfl_xor(p1, 2);
        p0 += __shfl_xor(p0, 4); p1 += __shfl_xor(p1, 4);
        p0 += __shfl_xor(p0, 8); p1 += __shfl_xor(p1, 8);
        float d0 = p0 - m, d1 = p1 - m;
        if (__any(fmaxf(d0, d1) > 8.f)) {
            float mn = fmaxf(m, fmaxf(p0, p1));
            float cf = __expf(m - mn);
            s *= cf; acc *= cf;
            m = mn;
            d0 = p0 - m; d1 = p1 - m;
        }
        float e0 = __expf(d0), e1 = __expf(d1);
        s += e0 + e1;
        acc = fmaf(e1, c1, fmaf(e0, c0, acc));
    }
    if (i < end) {
        float c0 = x0;
        float g0 = c0 + xrv;
        float p0 = attv * fmaxf(g0, NEG_SLOPE * g0);
        p0 += __shfl_xor(p0, 1);
        p0 += __shfl_xor(p0, 2);
        p0 += __shfl_xor(p0, 4);
        p0 += __shfl_xor(p0, 8);
        float d0 = p0 - m;
        if (__any(d0 > 8.f)) {
            float mn = fmaxf(m, p0);
            float cf = __expf(m - mn);
            s *= cf; acc *= cf;
            m = mn;
            d0 = p0 - m;
        }
        float e0 = __expf(d0);
        s += e0;
        acc = fmaf(e0, c0, acc);
    }
    float v = acc / (s + 1e-16f) + bv;
    float mx = v;
    mx = fmaxf(mx, __shfl_xor(mx, 1));
    mx = fmaxf(mx, __shfl_xor(mx, 2));
    mx = fmaxf(mx, __shfl_xor(mx, 4));
    mx = fmaxf(mx, __shfl_xor(mx, 8));
    float ex = __expf(v - mx);
    float se = ex;
    se += __shfl_xor(se, 1);
    se += __shfl_xor(se, 2);
    se += __shfl_xor(se, 4);
    se += __shfl_xor(se, 8);
    out[(size_t)n * 16 + gl] = v - mx - __logf(se);
}

// ---------------- launch ----------------

extern "C" void kernel_launch(void* const* d_in, const int* in_sizes, int n_in,
                              void* d_out, int out_size, void* d_ws, size_t ws_size,
                              hipStream_t stream) {
    const float* x    = (const float*)d_in[0];
    const int*   ei   = (const int*)d_in[1];
    const float* Wl1  = (const float*)d_in[2];
    const float* Wr1  = (const float*)d_in[3];
    const float* att1 = (const float*)d_in[4];
    const float* b1   = (const float*)d_in[5];
    const float* Wl2  = (const float*)d_in[6];
    const float* Wr2  = (const float*)d_in[7];
    const float* att2 = (const float*)d_in[8];
    const float* b2   = (const float*)d_in[9];
    const float* Wl3  = (const float*)d_in[10];
    const float* Wr3  = (const float*)d_in[11];
    const float* att3 = (const float*)d_in[12];
    const float* b3   = (const float*)d_in[13];
    const float* Wl4  = (const float*)d_in[14];
    const float* Wr4  = (const float*)d_in[15];
    const float* att4 = (const float*)d_in[16];
    const float* b4   = (const float*)d_in[17];

    const int N = in_sizes[0] / 128;
    const int E = in_sizes[1] / 2;
    const int* src = ei;
    const int* dst = ei + E;
    const int Etot = E + N;
    const int ntile = idiv(N, 128);

    char* wsb = (char*)d_ws;
    size_t off = 0;
    auto alloc = [&](size_t bytes) -> void* {
        void* p = wsb + off;
        off += (bytes + 255) & ~(size_t)255;
        return p;
    };
    f16*   PX   = (f16*)alloc((size_t)ntile * 128 * 128 * 2);
    f16*   PH   = (f16*)alloc((size_t)ntile * 128 * 256 * 2);
    f16*   xl16 = (f16*)alloc((size_t)N * 256 * 2);   // head-major [8][N][32]
    f16*   xr16 = (f16*)alloc((size_t)N * 256 * 2);   // head-major [8][N][32]
    float* xl4  = (float*)alloc((size_t)N * 16 * 4);
    float* xr4  = (float*)alloc((size_t)N * 16 * 4);
    f16*   PB1l = (f16*)alloc((size_t)256 * 128 * 2);
    f16*   PB1r = (f16*)alloc((size_t)256 * 128 * 2);
    f16*   PB2l = (f16*)alloc((size_t)256 * 256 * 2);
    f16*   PB2r = (f16*)alloc((size_t)256 * 256 * 2);
    f16*   PB3l = (f16*)alloc((size_t)256 * 256 * 2);
    f16*   PB3r = (f16*)alloc((size_t)256 * 256 * 2);
    int*   cnt  = (int*)alloc((size_t)N * 4);
    int*   wof  = (int*)alloc((size_t)N * 4);
    int*   rp   = (int*)alloc((size_t)(N + 1) * 4);
    int*   ss   = (int*)alloc((size_t)Etot * 4);
    int*   bsum = (int*)alloc((size_t)idiv(N, 1024) * 4);

    // conversions
    conv_x_packed<<<ntile, 256, 0, stream>>>(x, PX, N);
    convT_all<<<dim3(8, 8, 6), 256, 0, stream>>>(Wl1, Wr1, Wl2, Wr2, Wl3, Wr3,
                                                 PB1l, PB1r, PB2l, PB2r, PB3l, PB3r);

    // CSR build
    hipMemsetAsync(cnt, 0, (size_t)N * 4, stream);
    hist_kernel<<<idiv(Etot, 256), 256, 0, stream>>>(dst, E, N, cnt);
    const int nb = idiv(N, 1024);
    scanA<<<nb, 256, 0, stream>>>(cnt, bsum, N);
    scanB<<<1, 256, 0, stream>>>(bsum, nb);
    scanC<<<nb, 256, 0, stream>>>(cnt, bsum, rp, wof, N);
    scatter_kernel<<<idiv(Etot, 256), 256, 0, stream>>>(src, dst, E, N, wof, ss);

    const int nblk = ntile * 4;
    const int egrid = idiv(N, 64) * 8;
    // layer 1 (K=128)
    gemm16_packed<<<nblk, 256, 0, stream>>>(PX, N, 128, PB1l, PB1r, xl16, xr16);
    edge_h8_ns<<<egrid, 256, 0, stream>>>(xl16, xr16, rp, ss, att1, b1, PH, N);
    // layer 2
    gemm16_packed<<<nblk, 256, 0, stream>>>(PH, N, 256, PB2l, PB2r, xl16, xr16);
    edge_h8_ns<<<egrid, 256, 0, stream>>>(xl16, xr16, rp, ss, att2, b2, PH, N);
    // layer 3
    gemm16_packed<<<nblk, 256, 0, stream>>>(PH, N, 256, PB3l, PB3r, xl16, xr16);
    edge_h8_ns<<<egrid, 256, 0, stream>>>(xl16, xr16, rp, ss, att3, b3, PH, N);
    // layer 4 (M=16) + fused log_softmax
    gemm_small16<<<dim3(idiv(N, 16), 2), 256, 0, stream>>>(PH, N, Wl4, Wr4, xl4, xr4);
    edge_h1_kernel<<<idiv(N, 16), 256, 0, stream>>>(xl4, xr4, rp, ss, att4, b4,
                                                    (float*)d_out, N);
}